// Round 1
// baseline (380.068 us; speedup 1.0000x reference)
//
#include <hip/hip_runtime.h>
#include <hip/hip_bf16.h>
#include <math.h>

#define PSZ   147456           // pixels per sample (384*384)
#define NTOT  1179648          // 8 * PSZ
#define WW    384
#define HH    384
#define NIMG  8
#define NBIN  16384
#define INF2F 294913.0f        // H*H + W*W + 1
#define LEPS  1e-7f
#define G4    1024             // grid for elementwise kernels
#define G7    1024             // grid for lovasz kernel

// ---- exact, contraction-proof helpers (must be identical across kernels) ----
static __device__ __forceinline__ float errval(float x, float z) {
    // e = 1 - x * (2z - 1), computed with forced IEEE ops (no fma contraction)
    float s = __fsub_rn(__fmul_rn(2.0f, z), 1.0f);   // exactly +-1
    return __fsub_rn(1.0f, __fmul_rn(x, s));
}
static __device__ __forceinline__ int binof(float e) {
    int b = (int)(__fmul_rn(e, 2048.0f));            // e in (0, ~6.5] -> bin
    return b > (NBIN - 1) ? (NBIN - 1) : b;
}

// ---- K2: row EDT (exact 1D nearest-True distance via fwd/bwd scan) ----
__global__ __launch_bounds__(256) void k_edt_rows(const float* __restrict__ tgt,
                                                  float* __restrict__ g2f,
                                                  float* __restrict__ g2b) {
    int t = blockIdx.x * 256 + threadIdx.x;
    if (t >= NIMG * HH * 2) return;
    int pol = t & 1;                 // 0: fg EDT input, 1: bg EDT input
    int row = t >> 1;                // img*H + i
    const float* tr = tgt + (size_t)row * WW;
    float* out = (pol ? g2b : g2f) + (size_t)row * WW;
    int d = 600;
    for (int j = 0; j < WW; ++j) {
        bool f = tr[j] > 0.5f; if (pol) f = !f;
        d = f ? 0 : (d < 600 ? d + 1 : 600);
        out[j] = (float)d;           // temp: forward distance
    }
    d = 600;
    for (int j = WW - 1; j >= 0; --j) {
        bool f = tr[j] > 0.5f; if (pol) f = !f;
        d = f ? 0 : (d < 600 ? d + 1 : 600);
        int dm = (int)out[j]; if (d < dm) dm = d;
        out[j] = (dm <= 383) ? (float)(dm * dm) : INF2F;   // exact g2, INF2 if none
    }
}

// ---- K3: column EDT (brute-force min over i' with LDS tile) + dist + maxabs ----
__global__ __launch_bounds__(256) void k_edt_cols(const float* __restrict__ tgt,
                                                  const float* __restrict__ g2f,
                                                  const float* __restrict__ g2b,
                                                  float* __restrict__ dist,
                                                  unsigned int* __restrict__ maxabsBits) {
    // grid = NIMG * 24 * 2 = 384 blocks. Each block: one img, 16 columns, 192 rows.
    int blk  = blockIdx.x;
    int half = blk & 1;
    int jt   = (blk >> 1) % 24;
    int img  = blk / 48;
    int j0   = jt * 16;
    __shared__ float tf[HH * 16];
    __shared__ float tb[HH * 16];
    const float* gf = g2f + (size_t)img * PSZ;
    const float* gb = g2b + (size_t)img * PSZ;
    for (int l = threadIdx.x; l < HH * 16; l += 256) {
        int ii = l >> 4, jl = l & 15;
        int gidx = ii * WW + j0 + jl;
        tf[l] = gf[gidx];
        tb[l] = gb[gidx];
    }
    __syncthreads();
    int jl = threadIdx.x & 15;
    int i0 = threadIdx.x >> 4;           // 0..15
    int ibase = half * 192 + i0;         // output rows: ibase + 16k, k=0..11
    float accF[12], accB[12];
#pragma unroll
    for (int k = 0; k < 12; ++k) { accF[k] = INF2F; accB[k] = INF2F; }
    for (int ip = 0; ip < HH; ++ip) {
        float gF = tf[ip * 16 + jl];
        float gB = tb[ip * 16 + jl];
        float dd = (float)(ibase - ip);
#pragma unroll
        for (int k = 0; k < 12; ++k) {
            float q = dd * dd;                       // exact (integers < 2^24)
            accF[k] = fminf(accF[k], q + gF);
            accB[k] = fminf(accB[k], q + gB);
            dd += 16.0f;
        }
    }
    float am = 0.0f;
#pragma unroll
    for (int k = 0; k < 12; ++k) {
        int i = ibase + 16 * k;
        size_t o = (size_t)img * PSZ + (size_t)i * WW + j0 + jl;
        float df = sqrtf(fminf(accF[k], INF2F));     // pos (dist to fg)
        float db = sqrtf(fminf(accB[k], INF2F));     // neg (dist to bg)
        bool fg = tgt[o] > 0.5f;
        float dv = fg ? -db : df;                    // own-class dist is exactly 0
        dist[o] = dv;
        am = fmaxf(am, fabsf(dv));
    }
    __shared__ float red[256];
    red[threadIdx.x] = am; __syncthreads();
    for (int s = 128; s > 0; s >>= 1) {
        if (threadIdx.x < s) red[threadIdx.x] = fmaxf(red[threadIdx.x], red[threadIdx.x + s]);
        __syncthreads();
    }
    if (threadIdx.x == 0) atomicMax(maxabsBits, __float_as_uint(red[0]));
}

// ---- K4: elementwise pass: BCE/dice sums, per-sample P count, error histogram, sum p*dist ----
__global__ __launch_bounds__(256) void k_elem(const float* __restrict__ pred,
                                              const float* __restrict__ tgt,
                                              const float* __restrict__ dist,
                                              float* __restrict__ pBCE, float* __restrict__ pP,
                                              float* __restrict__ pPT, float* __restrict__ pBnd,
                                              unsigned int* __restrict__ Pcount,
                                              unsigned int* __restrict__ hist) {
    __shared__ unsigned int sc[NIMG];
    if (threadIdx.x < NIMG) sc[threadIdx.x] = 0;
    __syncthreads();
    float aB = 0.f, aP = 0.f, aPT = 0.f, aBD = 0.f;
    for (int n = blockIdx.x * 256 + threadIdx.x; n < NTOT; n += G4 * 256) {
        float x = pred[n];
        float z = tgt[n];
        float d = dist[n];
        float bce = fmaxf(x, 0.0f) - x * z + log1pf(expf(-fabsf(x)));
        float p = 1.0f / (1.0f + expf(-x));
        aB += bce; aP += p; aBD += p * d;
        bool lab = z > 0.5f;
        if (lab) aPT += p;
        int b = n / PSZ;
        if (lab) atomicAdd(&sc[b], 1u);
        float e = errval(x, z);
        if (e > 0.0f) {
            int bin = binof(e);
            atomicAdd(&hist[((size_t)b * NBIN + bin) * 2 + (lab ? 1 : 0)], 1u);
        }
    }
    __syncthreads();
    if (threadIdx.x < NIMG && sc[threadIdx.x]) atomicAdd(&Pcount[threadIdx.x], sc[threadIdx.x]);
    __shared__ float red[256];
    // 4 block reductions
    red[threadIdx.x] = aB; __syncthreads();
    for (int s = 128; s > 0; s >>= 1) { if (threadIdx.x < s) red[threadIdx.x] += red[threadIdx.x + s]; __syncthreads(); }
    if (threadIdx.x == 0) pBCE[blockIdx.x] = red[0];
    __syncthreads();
    red[threadIdx.x] = aP; __syncthreads();
    for (int s = 128; s > 0; s >>= 1) { if (threadIdx.x < s) red[threadIdx.x] += red[threadIdx.x + s]; __syncthreads(); }
    if (threadIdx.x == 0) pP[blockIdx.x] = red[0];
    __syncthreads();
    red[threadIdx.x] = aPT; __syncthreads();
    for (int s = 128; s > 0; s >>= 1) { if (threadIdx.x < s) red[threadIdx.x] += red[threadIdx.x + s]; __syncthreads(); }
    if (threadIdx.x == 0) pPT[blockIdx.x] = red[0];
    __syncthreads();
    red[threadIdx.x] = aBD; __syncthreads();
    for (int s = 128; s > 0; s >>= 1) { if (threadIdx.x < s) red[threadIdx.x] += red[threadIdx.x + s]; __syncthreads(); }
    if (threadIdx.x == 0) pBnd[blockIdx.x] = red[0];
}

// ---- K5: per-sample bin scan: scatter bases + suffix counts of pos/neg above each bin ----
__global__ __launch_bounds__(256) void k_scan(const unsigned int* __restrict__ hist,
                                              unsigned int* __restrict__ base,
                                              unsigned int* __restrict__ cnA,
                                              unsigned int* __restrict__ cpA,
                                              unsigned int* __restrict__ cntAll) {
    int b = blockIdx.x, t = threadIdx.x;
    const unsigned int* Hh = hist + (size_t)b * NBIN * 2;
    __shared__ unsigned int sN[257], sP[257], sT[257];
    unsigned int ln = 0, lp = 0;
    int m0 = t * 64;
    for (int m = m0; m < m0 + 64; ++m) { ln += Hh[m * 2]; lp += Hh[m * 2 + 1]; }
    sN[t] = ln; sP[t] = lp; sT[t] = ln + lp;
    __syncthreads();
    if (t == 0) {
        unsigned aN = 0, aP = 0, aT = 0;
        for (int i = 0; i < 256; ++i) {
            unsigned n = sN[i], p = sP[i], tt = sT[i];
            sN[i] = aN; sP[i] = aP; sT[i] = aT;
            aN += n; aP += p; aT += tt;
        }
        sN[256] = aN; sP[256] = aP; sT[256] = aT;
    }
    __syncthreads();
    unsigned totN = sN[256], totP = sP[256];
    unsigned runN = sN[t], runP = sP[t], runT = sT[t];
    size_t ob = (size_t)b * NBIN;
    for (int m = m0; m < m0 + 64; ++m) {
        unsigned hn = Hh[m * 2], hp = Hh[m * 2 + 1];
        base[ob + m] = runT;
        runN += hn; runP += hp; runT += hn + hp;
        cnA[ob + m] = totN - runN;     // negatives strictly in higher bins
        cpA[ob + m] = totP - runP;     // positives strictly in higher bins
    }
    if (t == 0) cntAll[b] = sT[256];
}

// ---- K6: scatter (e,label) into bucket-contiguous array; label in sign bit ----
__global__ __launch_bounds__(256) void k_scatter(const float* __restrict__ pred,
                                                 const float* __restrict__ tgt,
                                                 const unsigned int* __restrict__ base,
                                                 unsigned int* __restrict__ cnt,
                                                 float* __restrict__ SE) {
    for (int n = blockIdx.x * 256 + threadIdx.x; n < NTOT; n += G4 * 256) {
        float x = pred[n], z = tgt[n];
        float e = errval(x, z);
        if (e > 0.0f) {
            int b = n / PSZ;
            int bin = binof(e);
            size_t idx = (size_t)b * NBIN + bin;
            unsigned slot = base[idx] + atomicAdd(&cnt[idx], 1u);
            SE[(size_t)b * PSZ + slot] = (z > 0.5f) ? -e : e;   // positives negative-signed
        }
    }
}

// ---- K7: per-element Lovasz terms via bucket rank-counting (sort-free) ----
__global__ __launch_bounds__(256) void k_lovasz(const float* __restrict__ SE,
                                                const unsigned int* __restrict__ base,
                                                const unsigned int* __restrict__ cnt,
                                                const unsigned int* __restrict__ cnA,
                                                const unsigned int* __restrict__ cpA,
                                                const unsigned int* __restrict__ cntAll,
                                                const unsigned int* __restrict__ Pcount,
                                                float* __restrict__ pLov) {
    float acc = 0.0f;
    for (int s = blockIdx.x * 256 + threadIdx.x; s < NTOT; s += G7 * 256) {
        int b = s / PSZ;
        int sl = s - b * PSZ;
        if (sl >= (int)cntAll[b]) continue;
        const float* seb = SE + (size_t)b * PSZ;
        float v = seb[sl];
        float e = fabsf(v);
        bool pos = v < 0.0f;
        int bin = binof(e);
        size_t idx = (size_t)b * NBIN + bin;
        int lo = (int)base[idx];
        int hi = lo + (int)cnt[idx];
        int negGT = 0, posGE = 0, tieB = 0;
        for (int q = lo; q < hi; ++q) {
            float w = seb[q];
            negGT += (w > e);                    // negative (stored +) with value > e
            posGE += (w <= -e);                  // positive (stored -) with value >= e
            tieB  += (w == e && q < sl);         // tied negative with smaller slot
        }
        float P = (float)Pcount[b];
        float A = (float)(cnA[idx] + (unsigned)negGT);   // negatives strictly above me
        float term;
        if (pos) {
            term = e / (P + A + LEPS);
        } else {
            float cp = (float)(cpA[idx] + (unsigned)posGE);
            float U  = P + A + (float)tieB + 1.0f;       // P + cn_k
            term = e * (P - cp) / ((U - 1.0f + LEPS) * (U + LEPS));
        }
        acc += term;
    }
    __shared__ float red[256];
    red[threadIdx.x] = acc; __syncthreads();
    for (int st = 128; st > 0; st >>= 1) { if (threadIdx.x < st) red[threadIdx.x] += red[threadIdx.x + st]; __syncthreads(); }
    if (threadIdx.x == 0) pLov[blockIdx.x] = red[0];
}

// ---- K8: final combine (deterministic f64 reduce of partials) ----
__global__ __launch_bounds__(256) void k_final(const float* __restrict__ pB, const float* __restrict__ pP,
                                               const float* __restrict__ pPT, const float* __restrict__ pBnd,
                                               const float* __restrict__ pLov,
                                               const unsigned int* __restrict__ Pcount,
                                               const unsigned int* __restrict__ maxabsBits,
                                               float* __restrict__ out) {
    __shared__ double red[256];
    __shared__ double res[5];
    const float* arrs[5] = {pB, pP, pPT, pBnd, pLov};
    for (int a = 0; a < 5; ++a) {
        double sum = 0.0;
        for (int i = threadIdx.x; i < G4; i += 256) sum += (double)arrs[a][i];
        red[threadIdx.x] = sum; __syncthreads();
        for (int st = 128; st > 0; st >>= 1) { if (threadIdx.x < st) red[threadIdx.x] += red[threadIdx.x + st]; __syncthreads(); }
        if (threadIdx.x == 0) res[a] = red[0];
        __syncthreads();
    }
    if (threadIdx.x == 0) {
        double sumBCE = res[0], sumP = res[1], sumPT = res[2], sumBD = res[3], sumLV = res[4];
        double tsum = 0.0;
        for (int b = 0; b < NIMG; ++b) tsum += (double)Pcount[b];
        double bce = sumBCE / (double)NTOT;
        double dice = 1.0 - (2.0 * sumPT + 1.0) / (sumP + tsum + 1.0);
        float ma = __uint_as_float(maxabsBits[0]);
        double bnd = sumBD / (double)NTOT;
        if (ma > 0.0f) bnd = bnd / (double)ma;
        double lov = sumLV / (double)NIMG;
        double loss = 0.3 * bce + 0.3 * dice + 0.2 * bnd + 0.2 * lov;
        if (loss < 0.0) loss = 0.0;
        if (loss > 100.0) loss = 100.0;
        out[0] = (float)loss;
    }
}

extern "C" void kernel_launch(void* const* d_in, const int* in_sizes, int n_in,
                              void* d_out, int out_size, void* d_ws, size_t ws_size,
                              hipStream_t stream) {
    const float* pred = (const float*)d_in[0];
    const float* tgt  = (const float*)d_in[1];
    char* ws = (char*)d_ws;

    size_t off = 0;
    unsigned int* hist       = (unsigned int*)(ws + off); off += (size_t)NIMG * NBIN * 2 * 4; // 1 MB
    unsigned int* cnt        = (unsigned int*)(ws + off); off += (size_t)NIMG * NBIN * 4;     // 512 KB
    unsigned int* Pcount     = (unsigned int*)(ws + off); off += 32;
    unsigned int* cntAll     = (unsigned int*)(ws + off); off += 32;
    unsigned int* maxabsBits = (unsigned int*)(ws + off); off += 64;
    float* pBCE = (float*)(ws + off); off += G4 * 4;
    float* pP   = (float*)(ws + off); off += G4 * 4;
    float* pPT  = (float*)(ws + off); off += G4 * 4;
    float* pBnd = (float*)(ws + off); off += G4 * 4;
    float* pLov = (float*)(ws + off); off += G7 * 4;
    size_t zeroBytes = off;
    off = (off + 1023) & ~(size_t)1023;
    float* g2f  = (float*)(ws + off); off += (size_t)NIMG * PSZ * 4;
    float* g2b  = (float*)(ws + off); off += (size_t)NIMG * PSZ * 4;
    float* dist = (float*)(ws + off); off += (size_t)NIMG * PSZ * 4;
    unsigned int* base = (unsigned int*)(ws + off); off += (size_t)NIMG * NBIN * 4;
    unsigned int* cnA  = (unsigned int*)(ws + off); off += (size_t)NIMG * NBIN * 4;
    unsigned int* cpA  = (unsigned int*)(ws + off); off += (size_t)NIMG * NBIN * 4;
    float* SE   = (float*)(ws + off); off += (size_t)NIMG * PSZ * 4;
    (void)off; (void)ws_size; (void)in_sizes; (void)n_in; (void)out_size;

    hipMemsetAsync(d_ws, 0, zeroBytes, stream);
    k_edt_rows<<<(NIMG * HH * 2 + 255) / 256, 256, 0, stream>>>(tgt, g2f, g2b);
    k_edt_cols<<<NIMG * 24 * 2, 256, 0, stream>>>(tgt, g2f, g2b, dist, maxabsBits);
    k_elem<<<G4, 256, 0, stream>>>(pred, tgt, dist, pBCE, pP, pPT, pBnd, Pcount, hist);
    k_scan<<<NIMG, 256, 0, stream>>>(hist, base, cnA, cpA, cntAll);
    k_scatter<<<G4, 256, 0, stream>>>(pred, tgt, base, cnt, SE);
    k_lovasz<<<G7, 256, 0, stream>>>(SE, base, cnt, cnA, cpA, cntAll, Pcount, pLov);
    k_final<<<1, 256, 0, stream>>>(pBCE, pP, pPT, pBnd, pLov, Pcount, maxabsBits, (float*)d_out);
}

// Round 2
// 262.647 us; speedup vs baseline: 1.4471x; 1.4471x over previous
//
#include <hip/hip_runtime.h>
#include <hip/hip_bf16.h>
#include <math.h>

#define PSZ   147456           // pixels per sample (384*384)
#define NTOT  1179648          // 8 * PSZ
#define WW    384
#define HH    384
#define NIMG  8
#define NBIN  16384
#define INF2F 294913.0f        // H*H + W*W + 1
#define LEPS  1e-7f
#define G4    1024             // grid for elementwise kernels
#define G7    1024             // grid for lovasz kernel

// ---- exact, contraction-proof helpers (must be identical across kernels) ----
static __device__ __forceinline__ float errval(float x, float z) {
    // e = 1 - x * (2z - 1), computed with forced IEEE ops (no fma contraction)
    float s = __fsub_rn(__fmul_rn(2.0f, z), 1.0f);   // exactly +-1
    return __fsub_rn(1.0f, __fmul_rn(x, s));
}
static __device__ __forceinline__ int binof(float e) {
    int b = (int)(__fmul_rn(e, 2048.0f));            // e in (0, ~6.5] -> bin
    return b > (NBIN - 1) ? (NBIN - 1) : b;
}

// ---- K2: horizontal nearest-fg/bg distance per pixel, early-terminating (exact) ----
__global__ __launch_bounds__(256) void k_edt_h(const float* __restrict__ tgt,
                                               float* __restrict__ g2f,
                                               float* __restrict__ g2b) {
    int n = blockIdx.x * 256 + threadIdx.x;
    if (n >= NTOT) return;
    int rem = n % PSZ;
    int j = rem % WW;
    const float* tr = tgt + (size_t)(n - j);         // row base
    int rf = -1, rb = -1;
    if (tr[j] > 0.5f) rf = 0; else rb = 0;
    for (int r = 1; (rf < 0 || rb < 0) && r < WW; ++r) {
        int jl = j - r, jr = j + r;
        if (jl >= 0) {
            bool f = tr[jl] > 0.5f;
            if (f) { if (rf < 0) rf = r; } else { if (rb < 0) rb = r; }
        }
        if (jr < WW) {
            bool f = tr[jr] > 0.5f;
            if (f) { if (rf < 0) rf = r; } else { if (rb < 0) rb = r; }
        }
    }
    g2f[n] = (rf >= 0) ? (float)(rf * rf) : INF2F;   // exact squared row-distance
    g2b[n] = (rb >= 0) ? (float)(rb * rb) : INF2F;
}

// ---- K3: vertical combine with early termination (exact) + dist + maxabs ----
__global__ __launch_bounds__(256) void k_edt_v(const float* __restrict__ tgt,
                                               const float* __restrict__ g2f,
                                               const float* __restrict__ g2b,
                                               float* __restrict__ dist,
                                               unsigned int* __restrict__ maxabsBits) {
    int n = blockIdx.x * 256 + threadIdx.x;
    float am = 0.0f;
    if (n < NTOT) {
        int rem = n % PSZ;
        int i = rem / WW;
        int j = rem - i * WW;
        size_t rowbase = (size_t)(n - rem);          // img * PSZ
        const float* gf = g2f + rowbase;
        const float* gb = g2b + rowbase;
        float aF = gf[(size_t)i * WW + j];
        float aB = gb[(size_t)i * WW + j];
        for (int r = 1; r < HH; ++r) {
            float r2 = (float)(r * r);               // exact integer square
            if (r2 >= aF && r2 >= aB) break;         // no further i' can improve
            int up = i - r, dn = i + r;
            if (up >= 0) {
                size_t o = (size_t)up * WW + j;
                aF = fminf(aF, r2 + gf[o]);
                aB = fminf(aB, r2 + gb[o]);
            }
            if (dn < HH) {
                size_t o = (size_t)dn * WW + j;
                aF = fminf(aF, r2 + gf[o]);
                aB = fminf(aB, r2 + gb[o]);
            }
        }
        float df = sqrtf(fminf(aF, INF2F));          // dist to nearest fg
        float db = sqrtf(fminf(aB, INF2F));          // dist to nearest bg
        bool fg = tgt[n] > 0.5f;
        float dv = fg ? -db : df;                    // own-class dist is exactly 0
        dist[n] = dv;
        am = fabsf(dv);
    }
    __shared__ float red[256];
    red[threadIdx.x] = am; __syncthreads();
    for (int s = 128; s > 0; s >>= 1) {
        if (threadIdx.x < s) red[threadIdx.x] = fmaxf(red[threadIdx.x], red[threadIdx.x + s]);
        __syncthreads();
    }
    if (threadIdx.x == 0) atomicMax(maxabsBits, __float_as_uint(red[0]));
}

// ---- K4: elementwise pass: BCE/dice sums, per-sample P count, error histogram, sum p*dist ----
__global__ __launch_bounds__(256) void k_elem(const float* __restrict__ pred,
                                              const float* __restrict__ tgt,
                                              const float* __restrict__ dist,
                                              float* __restrict__ pBCE, float* __restrict__ pP,
                                              float* __restrict__ pPT, float* __restrict__ pBnd,
                                              unsigned int* __restrict__ Pcount,
                                              unsigned int* __restrict__ hist) {
    __shared__ unsigned int sc[NIMG];
    if (threadIdx.x < NIMG) sc[threadIdx.x] = 0;
    __syncthreads();
    float aB = 0.f, aP = 0.f, aPT = 0.f, aBD = 0.f;
    for (int n = blockIdx.x * 256 + threadIdx.x; n < NTOT; n += G4 * 256) {
        float x = pred[n];
        float z = tgt[n];
        float d = dist[n];
        float bce = fmaxf(x, 0.0f) - x * z + log1pf(expf(-fabsf(x)));
        float p = 1.0f / (1.0f + expf(-x));
        aB += bce; aP += p; aBD += p * d;
        bool lab = z > 0.5f;
        if (lab) aPT += p;
        int b = n / PSZ;
        if (lab) atomicAdd(&sc[b], 1u);
        float e = errval(x, z);
        if (e > 0.0f) {
            int bin = binof(e);
            atomicAdd(&hist[((size_t)b * NBIN + bin) * 2 + (lab ? 1 : 0)], 1u);
        }
    }
    __syncthreads();
    if (threadIdx.x < NIMG && sc[threadIdx.x]) atomicAdd(&Pcount[threadIdx.x], sc[threadIdx.x]);
    __shared__ float red[256];
    // 4 block reductions
    red[threadIdx.x] = aB; __syncthreads();
    for (int s = 128; s > 0; s >>= 1) { if (threadIdx.x < s) red[threadIdx.x] += red[threadIdx.x + s]; __syncthreads(); }
    if (threadIdx.x == 0) pBCE[blockIdx.x] = red[0];
    __syncthreads();
    red[threadIdx.x] = aP; __syncthreads();
    for (int s = 128; s > 0; s >>= 1) { if (threadIdx.x < s) red[threadIdx.x] += red[threadIdx.x + s]; __syncthreads(); }
    if (threadIdx.x == 0) pP[blockIdx.x] = red[0];
    __syncthreads();
    red[threadIdx.x] = aPT; __syncthreads();
    for (int s = 128; s > 0; s >>= 1) { if (threadIdx.x < s) red[threadIdx.x] += red[threadIdx.x + s]; __syncthreads(); }
    if (threadIdx.x == 0) pPT[blockIdx.x] = red[0];
    __syncthreads();
    red[threadIdx.x] = aBD; __syncthreads();
    for (int s = 128; s > 0; s >>= 1) { if (threadIdx.x < s) red[threadIdx.x] += red[threadIdx.x + s]; __syncthreads(); }
    if (threadIdx.x == 0) pBnd[blockIdx.x] = red[0];
}

// ---- K5: per-sample bin scan: scatter bases + suffix counts of pos/neg above each bin ----
__global__ __launch_bounds__(256) void k_scan(const unsigned int* __restrict__ hist,
                                              unsigned int* __restrict__ base,
                                              unsigned int* __restrict__ cnA,
                                              unsigned int* __restrict__ cpA,
                                              unsigned int* __restrict__ cntAll) {
    int b = blockIdx.x, t = threadIdx.x;
    const unsigned int* Hh = hist + (size_t)b * NBIN * 2;
    __shared__ unsigned int sN[257], sP[257], sT[257];
    unsigned int ln = 0, lp = 0;
    int m0 = t * 64;
    for (int m = m0; m < m0 + 64; ++m) { ln += Hh[m * 2]; lp += Hh[m * 2 + 1]; }
    sN[t] = ln; sP[t] = lp; sT[t] = ln + lp;
    __syncthreads();
    if (t == 0) {
        unsigned aN = 0, aP = 0, aT = 0;
        for (int i = 0; i < 256; ++i) {
            unsigned n = sN[i], p = sP[i], tt = sT[i];
            sN[i] = aN; sP[i] = aP; sT[i] = aT;
            aN += n; aP += p; aT += tt;
        }
        sN[256] = aN; sP[256] = aP; sT[256] = aT;
    }
    __syncthreads();
    unsigned totN = sN[256], totP = sP[256];
    unsigned runN = sN[t], runP = sP[t], runT = sT[t];
    size_t ob = (size_t)b * NBIN;
    for (int m = m0; m < m0 + 64; ++m) {
        unsigned hn = Hh[m * 2], hp = Hh[m * 2 + 1];
        base[ob + m] = runT;
        runN += hn; runP += hp; runT += hn + hp;
        cnA[ob + m] = totN - runN;     // negatives strictly in higher bins
        cpA[ob + m] = totP - runP;     // positives strictly in higher bins
    }
    if (t == 0) cntAll[b] = sT[256];
}

// ---- K6: scatter (e,label) into bucket-contiguous array; label in sign bit ----
__global__ __launch_bounds__(256) void k_scatter(const float* __restrict__ pred,
                                                 const float* __restrict__ tgt,
                                                 const unsigned int* __restrict__ base,
                                                 unsigned int* __restrict__ cnt,
                                                 float* __restrict__ SE) {
    for (int n = blockIdx.x * 256 + threadIdx.x; n < NTOT; n += G4 * 256) {
        float x = pred[n], z = tgt[n];
        float e = errval(x, z);
        if (e > 0.0f) {
            int b = n / PSZ;
            int bin = binof(e);
            size_t idx = (size_t)b * NBIN + bin;
            unsigned slot = base[idx] + atomicAdd(&cnt[idx], 1u);
            SE[(size_t)b * PSZ + slot] = (z > 0.5f) ? -e : e;   // positives negative-signed
        }
    }
}

// ---- K7: per-element Lovasz terms via bucket rank-counting (sort-free) ----
__global__ __launch_bounds__(256) void k_lovasz(const float* __restrict__ SE,
                                                const unsigned int* __restrict__ base,
                                                const unsigned int* __restrict__ cnt,
                                                const unsigned int* __restrict__ cnA,
                                                const unsigned int* __restrict__ cpA,
                                                const unsigned int* __restrict__ cntAll,
                                                const unsigned int* __restrict__ Pcount,
                                                float* __restrict__ pLov) {
    float acc = 0.0f;
    for (int s = blockIdx.x * 256 + threadIdx.x; s < NTOT; s += G7 * 256) {
        int b = s / PSZ;
        int sl = s - b * PSZ;
        if (sl >= (int)cntAll[b]) continue;
        const float* seb = SE + (size_t)b * PSZ;
        float v = seb[sl];
        float e = fabsf(v);
        bool pos = v < 0.0f;
        int bin = binof(e);
        size_t idx = (size_t)b * NBIN + bin;
        int lo = (int)base[idx];
        int hi = lo + (int)cnt[idx];
        int negGT = 0, posGE = 0, tieB = 0;
        for (int q = lo; q < hi; ++q) {
            float w = seb[q];
            negGT += (w > e);                    // negative (stored +) with value > e
            posGE += (w <= -e);                  // positive (stored -) with value >= e
            tieB  += (w == e && q < sl);         // tied negative with smaller slot
        }
        float P = (float)Pcount[b];
        float A = (float)(cnA[idx] + (unsigned)negGT);   // negatives strictly above me
        float term;
        if (pos) {
            term = e / (P + A + LEPS);
        } else {
            float cp = (float)(cpA[idx] + (unsigned)posGE);
            float U  = P + A + (float)tieB + 1.0f;       // P + cn_k
            term = e * (P - cp) / ((U - 1.0f + LEPS) * (U + LEPS));
        }
        acc += term;
    }
    __shared__ float red[256];
    red[threadIdx.x] = acc; __syncthreads();
    for (int st = 128; st > 0; st >>= 1) { if (threadIdx.x < st) red[threadIdx.x] += red[threadIdx.x + st]; __syncthreads(); }
    if (threadIdx.x == 0) pLov[blockIdx.x] = red[0];
}

// ---- K8: final combine (deterministic f64 reduce of partials) ----
__global__ __launch_bounds__(256) void k_final(const float* __restrict__ pB, const float* __restrict__ pP,
                                               const float* __restrict__ pPT, const float* __restrict__ pBnd,
                                               const float* __restrict__ pLov,
                                               const unsigned int* __restrict__ Pcount,
                                               const unsigned int* __restrict__ maxabsBits,
                                               float* __restrict__ out) {
    __shared__ double red[256];
    __shared__ double res[5];
    const float* arrs[5] = {pB, pP, pPT, pBnd, pLov};
    for (int a = 0; a < 5; ++a) {
        double sum = 0.0;
        for (int i = threadIdx.x; i < G4; i += 256) sum += (double)arrs[a][i];
        red[threadIdx.x] = sum; __syncthreads();
        for (int st = 128; st > 0; st >>= 1) { if (threadIdx.x < st) red[threadIdx.x] += red[threadIdx.x + st]; __syncthreads(); }
        if (threadIdx.x == 0) res[a] = red[0];
        __syncthreads();
    }
    if (threadIdx.x == 0) {
        double sumBCE = res[0], sumP = res[1], sumPT = res[2], sumBD = res[3], sumLV = res[4];
        double tsum = 0.0;
        for (int b = 0; b < NIMG; ++b) tsum += (double)Pcount[b];
        double bce = sumBCE / (double)NTOT;
        double dice = 1.0 - (2.0 * sumPT + 1.0) / (sumP + tsum + 1.0);
        float ma = __uint_as_float(maxabsBits[0]);
        double bnd = sumBD / (double)NTOT;
        if (ma > 0.0f) bnd = bnd / (double)ma;
        double lov = sumLV / (double)NIMG;
        double loss = 0.3 * bce + 0.3 * dice + 0.2 * bnd + 0.2 * lov;
        if (loss < 0.0) loss = 0.0;
        if (loss > 100.0) loss = 100.0;
        out[0] = (float)loss;
    }
}

extern "C" void kernel_launch(void* const* d_in, const int* in_sizes, int n_in,
                              void* d_out, int out_size, void* d_ws, size_t ws_size,
                              hipStream_t stream) {
    const float* pred = (const float*)d_in[0];
    const float* tgt  = (const float*)d_in[1];
    char* ws = (char*)d_ws;

    size_t off = 0;
    unsigned int* hist       = (unsigned int*)(ws + off); off += (size_t)NIMG * NBIN * 2 * 4; // 1 MB
    unsigned int* cnt        = (unsigned int*)(ws + off); off += (size_t)NIMG * NBIN * 4;     // 512 KB
    unsigned int* Pcount     = (unsigned int*)(ws + off); off += 32;
    unsigned int* cntAll     = (unsigned int*)(ws + off); off += 32;
    unsigned int* maxabsBits = (unsigned int*)(ws + off); off += 64;
    float* pBCE = (float*)(ws + off); off += G4 * 4;
    float* pP   = (float*)(ws + off); off += G4 * 4;
    float* pPT  = (float*)(ws + off); off += G4 * 4;
    float* pBnd = (float*)(ws + off); off += G4 * 4;
    float* pLov = (float*)(ws + off); off += G7 * 4;
    size_t zeroBytes = off;
    off = (off + 1023) & ~(size_t)1023;
    float* g2f  = (float*)(ws + off); off += (size_t)NIMG * PSZ * 4;
    float* g2b  = (float*)(ws + off); off += (size_t)NIMG * PSZ * 4;
    float* dist = (float*)(ws + off); off += (size_t)NIMG * PSZ * 4;
    unsigned int* base = (unsigned int*)(ws + off); off += (size_t)NIMG * NBIN * 4;
    unsigned int* cnA  = (unsigned int*)(ws + off); off += (size_t)NIMG * NBIN * 4;
    unsigned int* cpA  = (unsigned int*)(ws + off); off += (size_t)NIMG * NBIN * 4;
    float* SE   = (float*)(ws + off); off += (size_t)NIMG * PSZ * 4;
    (void)off; (void)ws_size; (void)in_sizes; (void)n_in; (void)out_size;

    hipMemsetAsync(d_ws, 0, zeroBytes, stream);
    k_edt_h<<<(NTOT + 255) / 256, 256, 0, stream>>>(tgt, g2f, g2b);
    k_edt_v<<<(NTOT + 255) / 256, 256, 0, stream>>>(tgt, g2f, g2b, dist, maxabsBits);
    k_elem<<<G4, 256, 0, stream>>>(pred, tgt, dist, pBCE, pP, pPT, pBnd, Pcount, hist);
    k_scan<<<NIMG, 256, 0, stream>>>(hist, base, cnA, cpA, cntAll);
    k_scatter<<<G4, 256, 0, stream>>>(pred, tgt, base, cnt, SE);
    k_lovasz<<<G7, 256, 0, stream>>>(SE, base, cnt, cnA, cpA, cntAll, Pcount, pLov);
    k_final<<<1, 256, 0, stream>>>(pBCE, pP, pPT, pBnd, pLov, Pcount, maxabsBits, (float*)d_out);
}

// Round 3
// 212.374 us; speedup vs baseline: 1.7896x; 1.2367x over previous
//
#include <hip/hip_runtime.h>
#include <hip/hip_bf16.h>
#include <math.h>

#define PSZ   147456           // pixels per sample (384*384)
#define NTOT  1179648          // 8 * PSZ
#define WW    384
#define HH    384
#define NIMG  8
#define NBIN  16384
#define INF2F 294913.0f        // H*H + W*W + 1
#define GV    4608             // NTOT / 256
#define BPS   576              // blocks per sample (PSZ / 256)

// ---- exact, contraction-proof helpers ----
static __device__ __forceinline__ float errval(float x, float z) {
    float s = __fsub_rn(__fmul_rn(2.0f, z), 1.0f);   // exactly +-1
    return __fsub_rn(1.0f, __fmul_rn(x, s));
}
static __device__ __forceinline__ int binof(float e) {
    int b = (int)(__fmul_rn(e, 2048.0f));
    return b > (NBIN - 1) ? (NBIN - 1) : b;
}
static __device__ __forceinline__ float bsum(float v, float* red, int t) {
    red[t] = v; __syncthreads();
    for (int s = 128; s > 0; s >>= 1) { if (t < s) red[t] += red[t + s]; __syncthreads(); }
    float r = red[0]; __syncthreads();
    return r;
}

// ---- K1: horizontal nearest-fg/bg squared distance, early-terminating (exact) ----
__global__ __launch_bounds__(256) void k_edt_h(const float* __restrict__ tgt,
                                               float* __restrict__ g2f,
                                               float* __restrict__ g2b) {
    int n = blockIdx.x * 256 + threadIdx.x;
    int rem = n % PSZ;
    int j = rem % WW;
    const float* tr = tgt + (size_t)(n - j);         // row base
    int rf = -1, rb = -1;
    if (tr[j] > 0.5f) rf = 0; else rb = 0;
    for (int r = 1; (rf < 0 || rb < 0) && r < WW; ++r) {
        int jl = j - r, jr = j + r;
        if (jl >= 0) {
            bool f = tr[jl] > 0.5f;
            if (f) { if (rf < 0) rf = r; } else { if (rb < 0) rb = r; }
        }
        if (jr < WW) {
            bool f = tr[jr] > 0.5f;
            if (f) { if (rf < 0) rf = r; } else { if (rb < 0) rb = r; }
        }
    }
    g2f[n] = (rf >= 0) ? (float)(rf * rf) : INF2F;
    g2b[n] = (rb >= 0) ? (float)(rb * rb) : INF2F;
}

// ---- K2: fused vertical EDT + all elementwise work ----
__global__ __launch_bounds__(256) void k_fused(const float* __restrict__ pred,
                                               const float* __restrict__ tgt,
                                               const float* __restrict__ g2f,
                                               const float* __restrict__ g2b,
                                               unsigned int* __restrict__ hcnt,
                                               unsigned long long* __restrict__ hsum,
                                               float* __restrict__ pB, float* __restrict__ pP,
                                               float* __restrict__ pPT, float* __restrict__ pBnd,
                                               unsigned int* __restrict__ pPc,
                                               unsigned int* __restrict__ maxabsBits) {
    int t = threadIdx.x;
    int n = blockIdx.x * 256 + t;
    int rem = n % PSZ;
    int i = rem / WW;
    int j = rem - i * WW;
    const float* gf = g2f + (size_t)(n - rem);
    const float* gb = g2b + (size_t)(n - rem);
    // vertical combine with exact early termination
    float aF = gf[rem];
    float aB = gb[rem];
    for (int r = 1; r < HH; ++r) {
        float r2 = (float)(r * r);
        if (r2 >= aF && r2 >= aB) break;
        int up = i - r, dn = i + r;
        if (up >= 0) { int o = up * WW + j; aF = fminf(aF, r2 + gf[o]); aB = fminf(aB, r2 + gb[o]); }
        if (dn < HH) { int o = dn * WW + j; aF = fminf(aF, r2 + gf[o]); aB = fminf(aB, r2 + gb[o]); }
    }
    float x = pred[n], z = tgt[n];
    bool lab = z > 0.5f;
    float df = sqrtf(fminf(aF, INF2F));              // dist to nearest fg
    float db = sqrtf(fminf(aB, INF2F));              // dist to nearest bg
    float dv = lab ? -db : df;                       // signed, unnormalized
    float bce = fmaxf(x, 0.0f) - x * z + log1pf(expf(-fabsf(x)));
    float p = 1.0f / (1.0f + expf(-x));
    // error histogram: count + exact fixed-point sum (e * 2^24 is exact for float e)
    float e = errval(x, z);
    if (e > 0.0f) {
        int bin = binof(e);
        int b = blockIdx.x / BPS;
        size_t idx = (((size_t)b * NBIN + bin) << 1) + (lab ? 1 : 0);
        atomicAdd(&hcnt[idx], 1u);
        atomicAdd(&hsum[idx], (unsigned long long)__fmul_rn(e, 16777216.0f));
    }
    // block reductions (deterministic)
    __shared__ float red[256];
    float sB  = bsum(bce, red, t);
    float sP  = bsum(p, red, t);
    float sPT = bsum(lab ? p : 0.0f, red, t);
    float sBD = bsum(p * dv, red, t);
    float sC  = bsum(lab ? 1.0f : 0.0f, red, t);     // exact integer count
    red[t] = fabsf(dv); __syncthreads();
    for (int s = 128; s > 0; s >>= 1) { if (t < s) red[t] = fmaxf(red[t], red[t + s]); __syncthreads(); }
    if (t == 0) {
        pB[blockIdx.x]  = sB;
        pP[blockIdx.x]  = sP;
        pPT[blockIdx.x] = sPT;
        pBnd[blockIdx.x] = sBD;
        pPc[blockIdx.x] = (unsigned int)(sC + 0.5f);
        atomicMax(maxabsBits, __float_as_uint(red[0]));
    }
}

// ---- K3: per-sample bin scan -> Lovasz via binned-tie closed form ----
__global__ __launch_bounds__(256) void k_scanlov(const unsigned int* __restrict__ hcnt,
                                                 const unsigned long long* __restrict__ hsum,
                                                 const unsigned int* __restrict__ pPc,
                                                 double* __restrict__ pLovD,
                                                 unsigned int* __restrict__ Pfin) {
    int b = blockIdx.x, t = threadIdx.x;
    // total positives for this sample (includes e<=0 ones)
    __shared__ unsigned int sred[256];
    unsigned int ps = 0;
    for (int q = t; q < BPS; q += 256) ps += pPc[b * BPS + q];
    sred[t] = ps; __syncthreads();
    for (int s = 128; s > 0; s >>= 1) { if (t < s) sred[t] += sred[t + s]; __syncthreads(); }
    unsigned int Pfull = sred[0];
    if (t == 0) Pfin[b] = Pfull;
    __syncthreads();
    double P = (double)Pfull;
    const unsigned int* hc = hcnt + ((size_t)b * NBIN << 1);
    const unsigned long long* hs = hsum + ((size_t)b * NBIN << 1);
    __shared__ unsigned int sN[257], sP2[257];
    unsigned int ln = 0, lp = 0;
    int m0 = t * 64;
    for (int m = m0; m < m0 + 64; ++m) { ln += hc[2 * m]; lp += hc[2 * m + 1]; }
    sN[t] = ln; sP2[t] = lp;
    __syncthreads();
    if (t == 0) {
        unsigned int aN = 0, aP = 0;
        for (int q = 0; q < 256; ++q) {
            unsigned int nn = sN[q], pp = sP2[q];
            sN[q] = aN; sP2[q] = aP;
            aN += nn; aP += pp;
        }
        sN[256] = aN; sP2[256] = aP;
    }
    __syncthreads();
    unsigned int totN = sN[256], totP = sP2[256];
    unsigned int runN = sN[t], runP = sP2[t];        // counts in bins < m
    const double EPS = 1e-7;
    const double SCL = 1.0 / 16777216.0;
    double l = 0.0;
    for (int m = m0; m < m0 + 64; ++m) {
        unsigned int hn = hc[2 * m], hp = hc[2 * m + 1];
        if (hn | hp) {
            double negAbove = (double)(totN - runN - hn);   // negatives in higher bins
            double D0 = P + negAbove + EPS;
            if (hp) {
                double sp = (double)hs[2 * m + 1] * SCL;
                l += sp / D0;                                // all bin positives share denom
            }
            if (hn) {
                double sn = (double)hs[2 * m] * SCL;
                double pAbove = (double)(totP - runP);       // positives above (incl. same bin)
                double D1 = D0 + (double)hn;
                l += (P - pAbove) * (sn / (double)hn) * (1.0 / D0 - 1.0 / D1);  // telescoped tie group
            }
            runN += hn; runP += hp;
        }
    }
    __shared__ double dred[256];
    dred[t] = l; __syncthreads();
    for (int s = 128; s > 0; s >>= 1) { if (t < s) dred[t] += dred[t + s]; __syncthreads(); }
    if (t == 0) pLovD[b] = dred[0];
}

// ---- K4: final combine (deterministic f64 reduce of partials) ----
__global__ __launch_bounds__(256) void k_final(const float* __restrict__ pB, const float* __restrict__ pP,
                                               const float* __restrict__ pPT, const float* __restrict__ pBnd,
                                               const double* __restrict__ pLovD,
                                               const unsigned int* __restrict__ Pfin,
                                               const unsigned int* __restrict__ maxabsBits,
                                               float* __restrict__ out) {
    __shared__ double red[256];
    __shared__ double res[4];
    const float* arrs[4] = {pB, pP, pPT, pBnd};
    int t = threadIdx.x;
    for (int a = 0; a < 4; ++a) {
        double sum = 0.0;
        for (int q = t; q < GV; q += 256) sum += (double)arrs[a][q];
        red[t] = sum; __syncthreads();
        for (int s = 128; s > 0; s >>= 1) { if (t < s) red[t] += red[t + s]; __syncthreads(); }
        if (t == 0) res[a] = red[0];
        __syncthreads();
    }
    if (t == 0) {
        double sumBCE = res[0], sumP = res[1], sumPT = res[2], sumBD = res[3];
        double tsum = 0.0, sumLV = 0.0;
        for (int b = 0; b < NIMG; ++b) { tsum += (double)Pfin[b]; sumLV += pLovD[b]; }
        double bce = sumBCE / (double)NTOT;
        double dice = 1.0 - (2.0 * sumPT + 1.0) / (sumP + tsum + 1.0);
        float ma = __uint_as_float(maxabsBits[0]);
        double bnd = sumBD / (double)NTOT;
        if (ma > 0.0f) bnd = bnd / (double)ma;
        double lov = sumLV / (double)NIMG;
        double loss = 0.3 * bce + 0.3 * dice + 0.2 * bnd + 0.2 * lov;
        if (loss < 0.0) loss = 0.0;
        if (loss > 100.0) loss = 100.0;
        out[0] = (float)loss;
    }
}

extern "C" void kernel_launch(void* const* d_in, const int* in_sizes, int n_in,
                              void* d_out, int out_size, void* d_ws, size_t ws_size,
                              hipStream_t stream) {
    const float* pred = (const float*)d_in[0];
    const float* tgt  = (const float*)d_in[1];
    char* ws = (char*)d_ws;

    size_t off = 0;
    unsigned int* hcnt = (unsigned int*)(ws + off);       off += (size_t)NIMG * NBIN * 2 * 4;  // 1 MB
    unsigned long long* hsum = (unsigned long long*)(ws + off); off += (size_t)NIMG * NBIN * 2 * 8; // 2 MB
    unsigned int* maxabsBits = (unsigned int*)(ws + off); off += 64;
    size_t zeroBytes = off;
    off = (off + 1023) & ~(size_t)1023;
    double* pLovD = (double*)(ws + off); off += NIMG * 8;
    unsigned int* Pfin = (unsigned int*)(ws + off); off += NIMG * 4;
    off = (off + 63) & ~(size_t)63;
    float* pB   = (float*)(ws + off); off += (size_t)GV * 4;
    float* pP   = (float*)(ws + off); off += (size_t)GV * 4;
    float* pPT  = (float*)(ws + off); off += (size_t)GV * 4;
    float* pBnd = (float*)(ws + off); off += (size_t)GV * 4;
    unsigned int* pPc = (unsigned int*)(ws + off); off += (size_t)GV * 4;
    off = (off + 1023) & ~(size_t)1023;
    float* g2f  = (float*)(ws + off); off += (size_t)NIMG * PSZ * 4;
    float* g2b  = (float*)(ws + off); off += (size_t)NIMG * PSZ * 4;
    (void)off; (void)ws_size; (void)in_sizes; (void)n_in; (void)out_size;

    hipMemsetAsync(d_ws, 0, zeroBytes, stream);
    k_edt_h<<<GV, 256, 0, stream>>>(tgt, g2f, g2b);
    k_fused<<<GV, 256, 0, stream>>>(pred, tgt, g2f, g2b, hcnt, hsum,
                                    pB, pP, pPT, pBnd, pPc, maxabsBits);
    k_scanlov<<<NIMG, 256, 0, stream>>>(hcnt, hsum, pPc, pLovD, Pfin);
    k_final<<<1, 256, 0, stream>>>(pB, pP, pPT, pBnd, pLovD, Pfin, maxabsBits, (float*)d_out);
}

// Round 4
// 120.565 us; speedup vs baseline: 3.1524x; 1.7615x over previous
//
#include <hip/hip_runtime.h>
#include <hip/hip_bf16.h>
#include <math.h>

#define PSZ   147456           // pixels per sample (384*384)
#define NTOT  1179648          // 8 * PSZ
#define WW    384
#define HH    384
#define NIMG  8
#define NBINH 4096             // histogram bins, width 1/512, covers e in (0,8)
#define INF2F 294913.0f        // H*H + W*W + 1
#define GV    4608             // NTOT / 256
#define BPS   576              // k_fused blocks per sample (PSZ / 256)
#define HBLK  128              // hist blocks (16 per sample)
#define HPXB  9216             // pixels per hist block (NTOT / HBLK)

// ---- exact, contraction-proof helpers ----
static __device__ __forceinline__ float errval(float x, float z) {
    float s = __fsub_rn(__fmul_rn(2.0f, z), 1.0f);   // exactly +-1
    return __fsub_rn(1.0f, __fmul_rn(x, s));
}
static __device__ __forceinline__ int binof(float e) {
    int b = (int)(__fmul_rn(e, 512.0f));
    return b > (NBINH - 1) ? (NBINH - 1) : b;
}

// nearest set bit distance -> exact squared distance (INF2F if none in row)
static __device__ __forceinline__ float g2word(const unsigned long long* m, int p) {
    int q = p >> 6, b = p & 63;
    int d = 1 << 20;
    unsigned long long t = m[q] >> b;                // bits >= p (incl. self)
    if (t) d = __builtin_ctzll(t);
    else {
        for (int u = q + 1; u < 6; ++u)
            if (m[u]) { d = u * 64 + __builtin_ctzll(m[u]) - p; break; }
    }
    int dl = 1 << 20;
    unsigned long long v = m[q] << (63 - b);         // bits <= p shifted so p->63
    if (v) dl = __builtin_clzll(v);
    else {
        for (int u = q - 1; u >= 0; --u)
            if (m[u]) { dl = p - (u * 64 + 63 - __builtin_clzll(m[u])); break; }
    }
    if (dl < d) d = dl;
    return (d <= 383) ? (float)(d * d) : INF2F;
}

// ---- K1: horizontal EDT via per-wave row bitmasks (ballot + ctz/clz, no scan loop) ----
__global__ __launch_bounds__(256) void k_edt_h(const float* __restrict__ tgt,
                                               float* __restrict__ g2f,
                                               float* __restrict__ g2b) {
    int row = blockIdx.x * 4 + (threadIdx.x >> 6);   // img*384 + i, 0..3071
    int l = threadIdx.x & 63;
    const float* tr = tgt + (size_t)row * WW;
    unsigned long long mf[6], mb[6];
#pragma unroll
    for (int c = 0; c < 6; ++c) {
        mf[c] = __ballot(tr[c * 64 + l] > 0.5f);     // wave-uniform row fg mask
        mb[c] = ~mf[c];                              // bg mask (row is exactly 384 bits)
    }
    size_t ob = (size_t)row * WW;
#pragma unroll
    for (int c = 0; c < 6; ++c) {
        int p = c * 64 + l;
        g2f[ob + p] = g2word(mf, p);
        g2b[ob + p] = g2word(mb, p);
    }
}

// ---- K2: fused vertical EDT + BCE/dice/boundary elementwise + reductions ----
__global__ __launch_bounds__(256) void k_fused(const float* __restrict__ pred,
                                               const float* __restrict__ tgt,
                                               const float* __restrict__ g2f,
                                               const float* __restrict__ g2b,
                                               float* __restrict__ pB, float* __restrict__ pP,
                                               float* __restrict__ pPT, float* __restrict__ pBnd,
                                               unsigned int* __restrict__ pPc,
                                               unsigned int* __restrict__ maxabsBits) {
    int t = threadIdx.x;
    int n = blockIdx.x * 256 + t;
    int rem = n % PSZ;
    int i = rem / WW;
    int j = rem - i * WW;
    const float* gf = g2f + (size_t)(n - rem);
    const float* gb = g2b + (size_t)(n - rem);
    // vertical combine with exact early termination
    float aF = gf[rem];
    float aB = gb[rem];
    for (int r = 1; r < HH; ++r) {
        float r2 = (float)(r * r);
        if (r2 >= aF && r2 >= aB) break;
        int up = i - r, dn = i + r;
        if (up >= 0) { int o = up * WW + j; aF = fminf(aF, r2 + gf[o]); aB = fminf(aB, r2 + gb[o]); }
        if (dn < HH) { int o = dn * WW + j; aF = fminf(aF, r2 + gf[o]); aB = fminf(aB, r2 + gb[o]); }
    }
    float x = pred[n], z = tgt[n];
    bool lab = z > 0.5f;
    float df = sqrtf(fminf(aF, INF2F));
    float db = sqrtf(fminf(aB, INF2F));
    float dv = lab ? -db : df;                       // signed, unnormalized
    float bce = fmaxf(x, 0.0f) - x * z + log1pf(expf(-fabsf(x)));
    float p = 1.0f / (1.0f + expf(-x));
    // wave butterfly reductions (fixed order -> deterministic)
    float vals[6];
    vals[0] = bce; vals[1] = p; vals[2] = lab ? p : 0.0f;
    vals[3] = p * dv; vals[4] = lab ? 1.0f : 0.0f; vals[5] = fabsf(dv);
#pragma unroll
    for (int k = 0; k < 5; ++k)
#pragma unroll
        for (int off = 32; off; off >>= 1) vals[k] += __shfl_xor(vals[k], off);
#pragma unroll
    for (int off = 32; off; off >>= 1) vals[5] = fmaxf(vals[5], __shfl_xor(vals[5], off));
    __shared__ float sw[4][6];
    int wv = t >> 6, ln = t & 63;
    if (ln == 0) {
#pragma unroll
        for (int k = 0; k < 6; ++k) sw[wv][k] = vals[k];
    }
    __syncthreads();
    if (t < 6) {
        int k = t;
        if (k == 5) {
            float a = fmaxf(fmaxf(sw[0][5], sw[1][5]), fmaxf(sw[2][5], sw[3][5]));
            atomicMax(maxabsBits, __float_as_uint(a));
        } else {
            float a = sw[0][k] + sw[1][k] + sw[2][k] + sw[3][k];
            if (k == 0) pB[blockIdx.x] = a;
            else if (k == 1) pP[blockIdx.x] = a;
            else if (k == 2) pPT[blockIdx.x] = a;
            else if (k == 3) pBnd[blockIdx.x] = a;
            else pPc[blockIdx.x] = (unsigned int)(a + 0.5f);
        }
    }
}

// ---- K3: LDS-aggregated error histogram (packed u64: count<<46 | sum(e*2^24)) ----
__global__ __launch_bounds__(1024) void k_hist(const float* __restrict__ pred,
                                               const float* __restrict__ tgt,
                                               unsigned long long* __restrict__ hist) {
    __shared__ unsigned long long h[NBINH * 2];
    for (int q = threadIdx.x; q < NBINH * 2; q += 1024) h[q] = 0ull;
    __syncthreads();
    int base = blockIdx.x * HPXB;
#pragma unroll
    for (int it = 0; it < HPXB / 1024; ++it) {       // 9 iterations
        int n = base + it * 1024 + threadIdx.x;
        float x = pred[n], z = tgt[n];
        float e = errval(x, z);
        if (e > 0.0f) {
            int lab = (z > 0.5f) ? 1 : 0;
            int bin = binof(e);
            unsigned long long add = (1ull << 46) |
                (unsigned long long)__fmul_rn(e, 16777216.0f);
            atomicAdd(&h[(bin << 1) + lab], add);
        }
    }
    __syncthreads();
    int s = blockIdx.x >> 4;                          // 16 blocks per sample
    unsigned long long* gh = hist + ((size_t)s * NBINH << 1);
    for (int q = threadIdx.x; q < NBINH * 2; q += 1024) {
        unsigned long long v = h[q];
        if (v) atomicAdd(&gh[q], v);                  // integer add: deterministic
    }
}

// ---- K4: per-sample bin scan -> Lovasz via binned-tie closed form ----
__global__ __launch_bounds__(256) void k_scanlov(const unsigned long long* __restrict__ hist,
                                                 const unsigned int* __restrict__ pPc,
                                                 double* __restrict__ pLovD,
                                                 unsigned int* __restrict__ Pfin) {
    int b = blockIdx.x, t = threadIdx.x;
    __shared__ unsigned int sred[256];
    unsigned int ps = 0;
    for (int q = t; q < BPS; q += 256) ps += pPc[b * BPS + q];
    sred[t] = ps; __syncthreads();
    for (int s = 128; s > 0; s >>= 1) { if (t < s) sred[t] += sred[t + s]; __syncthreads(); }
    unsigned int Pfull = sred[0];
    if (t == 0) Pfin[b] = Pfull;
    __syncthreads();
    double P = (double)Pfull;
    const unsigned long long* hc = hist + ((size_t)b * NBINH << 1);
    __shared__ unsigned int sN[257], sP2[257];
    unsigned int ln = 0, lp = 0;
    int m0 = t * (NBINH / 256);                      // 16 bins per thread
    for (int m = m0; m < m0 + 16; ++m) {
        ln += (unsigned int)(hc[2 * m] >> 46);
        lp += (unsigned int)(hc[2 * m + 1] >> 46);
    }
    sN[t] = ln; sP2[t] = lp;
    __syncthreads();
    if (t == 0) {
        unsigned int aN = 0, aP = 0;
        for (int q = 0; q < 256; ++q) {
            unsigned int nn = sN[q], pp = sP2[q];
            sN[q] = aN; sP2[q] = aP;
            aN += nn; aP += pp;
        }
        sN[256] = aN; sP2[256] = aP;
    }
    __syncthreads();
    unsigned int totN = sN[256], totP = sP2[256];
    unsigned int runN = sN[t], runP = sP2[t];        // counts in bins < m
    const double EPS = 1e-7;
    const double SCL = 1.0 / 16777216.0;
    const unsigned long long MSK = (1ull << 46) - 1;
    double l = 0.0;
    for (int m = m0; m < m0 + 16; ++m) {
        unsigned long long vn = hc[2 * m], vp = hc[2 * m + 1];
        unsigned int hn = (unsigned int)(vn >> 46), hp = (unsigned int)(vp >> 46);
        if (hn | hp) {
            double negAbove = (double)(totN - runN - hn);   // negatives in higher bins
            double D0 = P + negAbove + EPS;
            if (hp) {
                double sp = (double)(vp & MSK) * SCL;
                l += sp / D0;                                // bin positives share denom
            }
            if (hn) {
                double sn = (double)(vn & MSK) * SCL;
                double pAbove = (double)(totP - runP);       // positives ranked above group
                double D1 = D0 + (double)hn;
                l += (P - pAbove) * (sn / (double)hn) * (1.0 / D0 - 1.0 / D1);
            }
            runN += hn; runP += hp;
        }
    }
    __shared__ double dred[256];
    dred[t] = l; __syncthreads();
    for (int s = 128; s > 0; s >>= 1) { if (t < s) dred[t] += dred[t + s]; __syncthreads(); }
    if (t == 0) pLovD[b] = dred[0];
}

// ---- K5: final combine (deterministic f64 reduce of partials) ----
__global__ __launch_bounds__(256) void k_final(const float* __restrict__ pB, const float* __restrict__ pP,
                                               const float* __restrict__ pPT, const float* __restrict__ pBnd,
                                               const double* __restrict__ pLovD,
                                               const unsigned int* __restrict__ Pfin,
                                               const unsigned int* __restrict__ maxabsBits,
                                               float* __restrict__ out) {
    __shared__ double red[256];
    __shared__ double res[4];
    const float* arrs[4] = {pB, pP, pPT, pBnd};
    int t = threadIdx.x;
    for (int a = 0; a < 4; ++a) {
        double sum = 0.0;
        for (int q = t; q < GV; q += 256) sum += (double)arrs[a][q];
        red[t] = sum; __syncthreads();
        for (int s = 128; s > 0; s >>= 1) { if (t < s) red[t] += red[t + s]; __syncthreads(); }
        if (t == 0) res[a] = red[0];
        __syncthreads();
    }
    if (t == 0) {
        double sumBCE = res[0], sumP = res[1], sumPT = res[2], sumBD = res[3];
        double tsum = 0.0, sumLV = 0.0;
        for (int b = 0; b < NIMG; ++b) { tsum += (double)Pfin[b]; sumLV += pLovD[b]; }
        double bce = sumBCE / (double)NTOT;
        double dice = 1.0 - (2.0 * sumPT + 1.0) / (sumP + tsum + 1.0);
        float ma = __uint_as_float(maxabsBits[0]);
        double bnd = sumBD / (double)NTOT;
        if (ma > 0.0f) bnd = bnd / (double)ma;
        double lov = sumLV / (double)NIMG;
        double loss = 0.3 * bce + 0.3 * dice + 0.2 * bnd + 0.2 * lov;
        if (loss < 0.0) loss = 0.0;
        if (loss > 100.0) loss = 100.0;
        out[0] = (float)loss;
    }
}

extern "C" void kernel_launch(void* const* d_in, const int* in_sizes, int n_in,
                              void* d_out, int out_size, void* d_ws, size_t ws_size,
                              hipStream_t stream) {
    const float* pred = (const float*)d_in[0];
    const float* tgt  = (const float*)d_in[1];
    char* ws = (char*)d_ws;

    size_t off = 0;
    unsigned long long* hist = (unsigned long long*)(ws + off); off += (size_t)NIMG * NBINH * 2 * 8; // 512 KB
    unsigned int* maxabsBits = (unsigned int*)(ws + off); off += 64;
    size_t zeroBytes = off;
    off = (off + 1023) & ~(size_t)1023;
    double* pLovD = (double*)(ws + off); off += NIMG * 8;
    unsigned int* Pfin = (unsigned int*)(ws + off); off += NIMG * 4;
    off = (off + 63) & ~(size_t)63;
    float* pB   = (float*)(ws + off); off += (size_t)GV * 4;
    float* pP   = (float*)(ws + off); off += (size_t)GV * 4;
    float* pPT  = (float*)(ws + off); off += (size_t)GV * 4;
    float* pBnd = (float*)(ws + off); off += (size_t)GV * 4;
    unsigned int* pPc = (unsigned int*)(ws + off); off += (size_t)GV * 4;
    off = (off + 1023) & ~(size_t)1023;
    float* g2f  = (float*)(ws + off); off += (size_t)NIMG * PSZ * 4;
    float* g2b  = (float*)(ws + off); off += (size_t)NIMG * PSZ * 4;
    (void)off; (void)ws_size; (void)in_sizes; (void)n_in; (void)out_size;

    hipMemsetAsync(d_ws, 0, zeroBytes, stream);
    k_edt_h<<<NIMG * HH / 4, 256, 0, stream>>>(tgt, g2f, g2b);
    k_fused<<<GV, 256, 0, stream>>>(pred, tgt, g2f, g2b, pB, pP, pPT, pBnd, pPc, maxabsBits);
    k_hist<<<HBLK, 1024, 0, stream>>>(pred, tgt, hist);
    k_scanlov<<<NIMG, 256, 0, stream>>>(hist, pPc, pLovD, Pfin);
    k_final<<<1, 256, 0, stream>>>(pB, pP, pPT, pBnd, pLovD, Pfin, maxabsBits, (float*)d_out);
}